// Round 12
// baseline (606.633 us; speedup 1.0000x reference)
//
#include <hip/hip_runtime.h>
#include <hip/hip_bf16.h>

#define BB   4
#define HH   256
#define WW   256
#define INCH 128
#define MIDC 64
#define NPAT 4
#define PP   16
#define PS   64

typedef __bf16 bf16x8 __attribute__((ext_vector_type(8)));
typedef float f32x4 __attribute__((ext_vector_type(4)));
typedef unsigned short ushort_t;

#define UPL 16777216UL   // one 64-ch bf16 plane set: B*H*W*64 elements

__device__ inline ushort_t f2bf(float f) {
    unsigned u = __float_as_uint(f);
    unsigned r = (u + 0x7FFFu + ((u >> 16) & 1u)) >> 16;
    return (ushort_t)r;
}
__device__ inline float bf2f(ushort_t h) {
    return __uint_as_float(((unsigned)h) << 16);
}
__device__ inline f32x4 mfma16(uint4 a, uint4 b, f32x4 c) {
    return __builtin_amdgcn_mfma_f32_16x16x32_bf16(
        __builtin_bit_cast(bf16x8, a), __builtin_bit_cast(bf16x8, b), c, 0, 0, 0);
}

// ---------------------------------------------------------------------------
// fused prep: conv weights -> [9][COUT][CIN] bf16; p1/p2 -> bf16; zero
// n1/n2/dotv; pack c1_b/c2_b into cbias[2][3][64].
// ---------------------------------------------------------------------------
__global__ __launch_bounds__(256) void prep_all_kernel(
    const float* __restrict__ pre_w, const float* __restrict__ c1_w,
    const float* __restrict__ c2_w,  const float* __restrict__ fin_w,
    const float* __restrict__ p1_w,  const float* __restrict__ p2_w,
    const float* __restrict__ c1_b,  const float* __restrict__ c2_b,
    ushort_t* __restrict__ wpPre, ushort_t* __restrict__ wpC,
    ushort_t* __restrict__ wpFin, ushort_t* __restrict__ pw1b,
    ushort_t* __restrict__ pw2b,  float* __restrict__ zbuf,
    float* __restrict__ cbias)
{
    int idx = blockIdx.x * 256 + threadIdx.x;
    if (idx < 73728) {                       // pre: COUT=64, CIN=128
        int tap = idx % 9, ci = (idx / 9) % 128, co = idx / 1152;
        wpPre[(tap * 64 + co) * 128 + ci] = f2bf(pre_w[idx]);
    } else if (idx < 294912) {               // c1[0..2], c2[0..2]: 64x64
        int j = idx - 73728;
        int which = j / 36864, k = j % 36864;
        const float* src = (which < 3) ? (c1_w + (size_t)which * 36864)
                                       : (c2_w + (size_t)(which - 3) * 36864);
        int tap = k % 9, ci = (k / 9) % 64, co = k / 576;
        wpC[(size_t)which * 36864 + (tap * 64 + co) * 64 + ci] = f2bf(src[k]);
    } else if (idx < 442368) {               // fin: 128x128
        int k = idx - 294912;
        int tap = k % 9, ci = (k / 9) % 128, co = k / 1152;
        wpFin[(tap * 128 + co) * 128 + ci] = f2bf(fin_w[k]);
    } else if (idx < 507904) {
        pw1b[idx - 442368] = f2bf(p1_w[idx - 442368]);
    } else if (idx < 573440) {
        pw2b[idx - 507904] = f2bf(p2_w[idx - 507904]);
    } else if (idx < 574592) {
        zbuf[idx - 573440] = 0.f;            // n1(64)+n2(64)+dotv(1024)
    } else if (idx < 574784) {
        cbias[idx - 574592] = c1_b[idx - 574592];
    } else if (idx < 574976) {
        cbias[192 + idx - 574784] = c2_b[idx - 574784];
    }
}

// ---------------------------------------------------------------------------
// x fp32 NCHW -> bf16 NHWC  (LDS tile transpose: 64 px x 128 ch per block)
// ---------------------------------------------------------------------------
__global__ __launch_bounds__(256) void x_to_nhwc_kernel(
    const float* __restrict__ x, ushort_t* __restrict__ xh)
{
    __shared__ ushort_t sm[64 * 136];
    const int t = threadIdx.x;
    const int bx = blockIdx.x;             // 4096: b*1024 + pxtile
    const int b = bx >> 10;
    const int pxbase = (bx & 1023) * 64;
#pragma unroll
    for (int i = 0; i < 32; ++i) {
        int idx = i * 256 + t;             // [128 c][64 px]
        int c = idx >> 6, pxl = idx & 63;
        sm[pxl * 136 + c] = f2bf(x[((size_t)(b * 128 + c)) * 65536 + pxbase + pxl]);
    }
    __syncthreads();
#pragma unroll
    for (int i = 0; i < 4; ++i) {
        int idx = i * 256 + t;             // [64 px][16 quads]
        int pxl = idx >> 4, q = idx & 15;
        uint4 v = *(const uint4*)&sm[pxl * 136 + q * 8];
        *(uint4*)(xh + ((size_t)b * 65536 + pxbase + pxl) * 128 + q * 8) = v;
    }
}

// ---------------------------------------------------------------------------
// staging (wide tile): 32-ci slab with halo (6 rows x 68 px) into regs
// [408 px][4 quads] = 1632 uint4
// ---------------------------------------------------------------------------
template<int CIN, int CSPLIT>
__device__ inline void stage6x68(const ushort_t* inA, const ushort_t* inB,
                                 int b, int y0, int x0, int t, int cb,
                                 uint4 (&stg)[7])
{
#pragma unroll
    for (int i = 0; i < 7; ++i) {
        int e = i * 256 + t;
        int pxl = e >> 2, quad = e & 3;
        int row = pxl / 68, xl = pxl - row * 68;
        int gy = y0 + row - 1, gx = x0 + xl - 1;
        bool ok = (e < 1632) && ((unsigned)gy < 256u) && ((unsigned)gx < 256u);
        int c0 = cb + quad * 8;
        const ushort_t* src; int nch, ch;
        if ((CSPLIT == CIN) || (c0 < CSPLIT)) { src = inA; nch = CSPLIT; ch = c0; }
        else { src = inB; nch = CIN - CSPLIT; ch = c0 - CSPLIT; }
        uint4 v = make_uint4(0u, 0u, 0u, 0u);
        if (ok) v = *(const uint4*)(src + ((size_t)((b * 256 + gy) * 256 + gx)) * nch + ch);
        stg[i] = v;
    }
}

// ---------------------------------------------------------------------------
// wide conv (R3/R11 best geometry, ~120 VGPR -> 4 waves/SIMD, ALL convs):
// block tile 4 rows x 64 px x 64 co; wave = co-half x row-pair, 4 x-cols.
// s-outer inner loop with af[2][9] preload; stg[7] register prefetch.
// LDS [6 rows][68 px][32 ci] linear (known ~6e6 conflict cycles, accepted —
// measured cheaper than spending VGPRs on swizzle: R6 vs R11).
// XCD-chunked swizzle (grid.x % 8 == 0).
// COPAIR: co-halves of a tile adjacent post-swizzle (same XCD) -> 2nd
// staging fetch is an L2 hit (measured: FETCH 138->104 MB, R11).
// PAIR: blockIdx.y = branch; in/wgt/bias/out strided.
// OMODE: 0 = bf16 NHWC; 1 = + bf16 NHWC residual (post-relu);
//        2 = fp32 NCHW + fp32 NCHW residual (post-relu).
// ---------------------------------------------------------------------------
template<int CIN, int CSPLIT, int OMODE, bool PAIR, bool COPAIR>
__global__ __launch_bounds__(256) void wconv3x3(
    const ushort_t* __restrict__ inA, const ushort_t* __restrict__ inB,
    const ushort_t* __restrict__ wgtT,   // [9][COUT][CIN] bf16 (+ br*wStride)
    const float* __restrict__ bias,
    const void* __restrict__ res,        // bf16 (OMODE=1) / fp32 (OMODE=2), unstrided
    void* __restrict__ out,
    int COUT, size_t inStride, size_t wStride, size_t bStride, size_t outStride)
{
    constexpr int NCH = CIN / 32;
    __shared__ ushort_t sm[6 * 68 * 32];   // 26112 B

    const int t = threadIdx.x;
    const int nx = gridDim.x;              // % 8 == 0
    const int bid = blockIdx.x;
    const int fid = (bid & 7) * (nx >> 3) + (bid >> 3);   // chunked XCD swizzle
    int tile, cog;
    if (COPAIR) { tile = fid >> 1; cog = (fid & 1) * 64; }
    else        { tile = fid;      cog = PAIR ? 0 : blockIdx.y * 64; }
    const int y0 = (tile >> 2) * 4;        // 64 y-tiles
    const int x0 = (tile & 3) * 64;        // 4 x-tiles
    const int br = PAIR ? blockIdx.y : 0;
    const ushort_t* inAb = inA + (size_t)br * inStride;
    const ushort_t* inBb = inB + (size_t)br * inStride;
    const ushort_t* wgt  = wgtT + (size_t)br * wStride;
    const float*    bs   = bias + (size_t)br * bStride;
    const int b = blockIdx.z;
    const int l = t & 63, w = t >> 6;
    const int lan15 = l & 15;
    const int g4 = l >> 4;
    const int k8 = g4 * 8;
    const int co0 = cog + (w & 1) * 32;
    const int wrow0 = (w >> 1) * 2;

    f32x4 acc[2][8];
#pragma unroll
    for (int mt = 0; mt < 2; ++mt)
#pragma unroll
        for (int nt = 0; nt < 8; ++nt) acc[mt][nt] = (f32x4)0.f;

    uint4 stg[7];
    stage6x68<CIN, CSPLIT>(inAb, inBb, b, y0, x0, t, 0, stg);

    for (int cc = 0; cc < NCH; ++cc) {
        __syncthreads();
#pragma unroll
        for (int i = 0; i < 7; ++i) {
            int e = i * 256 + t;
            if (e < 1632) {
                int pxl = e >> 2, quad = e & 3;
                *(uint4*)&sm[pxl * 32 + quad * 8] = stg[i];
            }
        }
        __syncthreads();
        if (cc + 1 < NCH)
            stage6x68<CIN, CSPLIT>(inAb, inBb, b, y0, x0, t, (cc + 1) * 32, stg);

        const int cb = cc * 32;
        uint4 af[2][9];
#pragma unroll
        for (int mt = 0; mt < 2; ++mt)
#pragma unroll
            for (int tap = 0; tap < 9; ++tap)
                af[mt][tap] = *(const uint4*)(wgt +
                    ((size_t)tap * COUT + co0 + mt * 16 + lan15) * CIN + cb + k8);

#pragma unroll
        for (int rr = 0; rr < 4; ++rr) {
            const int r = wrow0 + rr;
#pragma unroll
            for (int col = 0; col < 4; ++col) {
#pragma unroll
                for (int dx = 0; dx < 3; ++dx) {
                    const int xc = col * 16 + lan15 + dx;
                    uint4 bv = *(const uint4*)&sm[(r * 68 + xc) * 32 + k8];
#pragma unroll
                    for (int drow = 0; drow < 2; ++drow) {
                        const int dy = rr - drow;
                        if (dy >= 0 && dy < 3) {
                            const int tap = dy * 3 + dx;
                            const int nt = drow * 4 + col;
                            acc[0][nt] = mfma16(af[0][tap], bv, acc[0][nt]);
                            acc[1][nt] = mfma16(af[1][tap], bv, acc[1][nt]);
                        }
                    }
                }
            }
        }
    }

    // epilogue
#pragma unroll
    for (int mt = 0; mt < 2; ++mt) {
#pragma unroll
        for (int nt = 0; nt < 8; ++nt) {
            const int y = y0 + wrow0 + (nt >> 2);
            const int x = x0 + (nt & 3) * 16 + lan15;
            const int codr = co0 + mt * 16 + g4 * 4;
            float v[4];
#pragma unroll
            for (int j = 0; j < 4; ++j)
                v[j] = fmaxf(acc[mt][nt][j] + bias[(size_t)br * bStride + codr + j], 0.f);
            if constexpr (OMODE == 2) {
                const float* rf = (const float*)res;
                float* of = (float*)out;
#pragma unroll
                for (int j = 0; j < 4; ++j) {
                    size_t oi = ((size_t)(b * COUT + codr + j) * 256 + y) * 256 + x;
                    of[oi] = v[j] + rf[oi];
                }
            } else {
                const size_t pix = (size_t)(b * 256 + y) * 256 + x;
                if constexpr (OMODE == 1) {
                    const ushort_t* rp = (const ushort_t*)res + pix * 64 + codr;
#pragma unroll
                    for (int j = 0; j < 4; ++j) v[j] += bf2f(rp[j]);
                }
                uint2 pk;
                pk.x = (unsigned)f2bf(v[0]) | ((unsigned)f2bf(v[1]) << 16);
                pk.y = (unsigned)f2bf(v[2]) | ((unsigned)f2bf(v[3]) << 16);
                *(uint2*)((ushort_t*)out + (size_t)br * outStride + pix * COUT + codr) = pk;
            }
        }
    }
}

// ---------------------------------------------------------------------------
// per-patch 1x1 conv via MFMA (bf16 NHWC -> bf16 NHWC) + fused norm atomics.
// blockIdx.z selects side (x1/x2).
// ---------------------------------------------------------------------------
__global__ __launch_bounds__(256) void patch1x1_mfma(
    const ushort_t* __restrict__ in0, const ushort_t* __restrict__ pwb0,
    const float* __restrict__ bias1, const float* __restrict__ bias2,
    ushort_t* __restrict__ outp0, float* __restrict__ nrm0)
{
    __shared__ ushort_t smp[256 * 72];
    const int side = blockIdx.z;
    const ushort_t* in  = in0  + (size_t)side * UPL;
    const ushort_t* pwb = pwb0 + side * 65536;
    const float*   bias = side ? bias2 : bias1;
    ushort_t*      outp = outp0 + (size_t)side * UPL;
    float*         nrm  = nrm0 + side * 64;

    const int t = threadIdx.x;
    const int bx = blockIdx.x;         // iy0 = bx*4
    const int bp = blockIdx.y;
    const int b = bp >> 4, p = bp & 15;
    const int py = (p >> 2) * 64, px0 = (p & 3) * 64;
    const int l = t & 63, w = t >> 6;
    const int lan15 = l & 15, k8 = (l >> 4) * 8;

#pragma unroll
    for (int i = 0; i < 8; ++i) {
        int idx = i * 256 + t;         // [256 px][8 quads]
        int px = idx >> 3, q = idx & 7;
        int y = py + bx * 4 + (px >> 6), x = px0 + (px & 63);
        uint4 v = *(const uint4*)(in + ((size_t)(b * 256 + y) * 256 + x) * 64 + q * 8);
        *(uint4*)&smp[px * 72 + q * 8] = v;
    }
    __syncthreads();

    uint4 af[4][2];
#pragma unroll
    for (int mt = 0; mt < 4; ++mt)
#pragma unroll
        for (int kk = 0; kk < 2; ++kk)
            af[mt][kk] = *(const uint4*)(pwb + (size_t)p * 4096 +
                                         (mt * 16 + lan15) * 64 + kk * 32 + k8);

    f32x4 acc[4][4];
#pragma unroll
    for (int mt = 0; mt < 4; ++mt)
#pragma unroll
        for (int j = 0; j < 4; ++j) acc[mt][j] = (f32x4)0.f;

#pragma unroll
    for (int kk = 0; kk < 2; ++kk)
#pragma unroll
        for (int j = 0; j < 4; ++j) {
            int px = (w * 4 + j) * 16 + lan15;
            uint4 bv = *(const uint4*)&smp[px * 72 + kk * 32 + k8];
#pragma unroll
            for (int mt = 0; mt < 4; ++mt)
                acc[mt][j] = mfma16(af[mt][kk], bv, acc[mt][j]);
        }

    float nsum = 0.f;
#pragma unroll
    for (int mt = 0; mt < 4; ++mt)
#pragma unroll
        for (int j = 0; j < 4; ++j) {
            int px = (w * 4 + j) * 16 + lan15;
            int y = py + bx * 4 + (px >> 6), x = px0 + (px & 63);
            int d0 = mt * 16 + (l >> 4) * 4;
            float v[4];
#pragma unroll
            for (int r = 0; r < 4; ++r) {
                v[r] = acc[mt][j][r] + bias[p * 64 + d0 + r];
                nsum = fmaf(v[r], v[r], nsum);
            }
            uint2 pk;
            pk.x = (unsigned)f2bf(v[0]) | ((unsigned)f2bf(v[1]) << 16);
            pk.y = (unsigned)f2bf(v[2]) | ((unsigned)f2bf(v[3]) << 16);
            *(uint2*)(outp + ((size_t)(b * 256 + y) * 256 + x) * 64 + d0) = pk;
        }

#pragma unroll
    for (int off = 32; off > 0; off >>= 1) nsum += __shfl_down(nsum, off);
    if (l == 0) atomicAdd(&nrm[b * 16 + p], nsum);
}

// ---------------------------------------------------------------------------
// pairwise patch dots via MFMA: dotv[b][p][q] += f1_p . f2_q
// ---------------------------------------------------------------------------
__global__ __launch_bounds__(256) void patch_dots_mfma(
    const ushort_t* __restrict__ f1, const ushort_t* __restrict__ f2,
    float* __restrict__ dotv)
{
    __shared__ float rbuf[4][64][4];
    const int t = threadIdx.x;
    const int kb = blockIdx.x;         // patch-local row iy
    const int b = blockIdx.y;
    const int l = t & 63, w = t >> 6;
    const int lan15 = l & 15, k8q = (l >> 4) * 8;
    const int p = lan15;
    const int py = (p >> 2) * 64, px0 = (p & 3) * 64;
    const size_t rowbase = ((size_t)(b * 256 + py + kb) * 256 + px0) * 64;

    f32x4 acc = (f32x4)0.f;
    for (int ixl = 0; ixl < 16; ++ixl) {
        const size_t pa = rowbase + (size_t)(w * 16 + ixl) * 64 + k8q;
#pragma unroll
        for (int c0 = 0; c0 < 64; c0 += 32) {
            uint4 av = *(const uint4*)(f1 + pa + c0);
            uint4 bv = *(const uint4*)(f2 + pa + c0);
            acc = mfma16(av, bv, acc);
        }
    }
#pragma unroll
    for (int r = 0; r < 4; ++r) rbuf[w][l][r] = acc[r];
    __syncthreads();
    if (t < 64) {
#pragma unroll
        for (int r = 0; r < 4; ++r) {
            float s = rbuf[0][t][r] + rbuf[1][t][r] + rbuf[2][t][r] + rbuf[3][t][r];
            int pp = (t >> 4) * 4 + r, qq = t & 15;
            atomicAdd(&dotv[b * 256 + pp * 16 + qq], s);
        }
    }
}

// ---------------------------------------------------------------------------
// attention weights: d = n1+n2-2dot, diag=1e8, attn = softmax(exp(-d))
// ---------------------------------------------------------------------------
__global__ __launch_bounds__(1024) void attn_kernel(
    const float* __restrict__ n1, const float* __restrict__ n2,
    const float* __restrict__ dotv, float* __restrict__ attn)
{
    __shared__ float tv[1024];
    int t = threadIdx.x;
    int b = t >> 8, p = (t >> 4) & 15, q = t & 15;
    float d = n1[b * 16 + p] + n2[b * 16 + q] - 2.f * dotv[t];
    if (p == q) d = 1e8f;
    float e = expf(-d);
    tv[t] = e;
    __syncthreads();
    const float* row = &tv[(t >> 4) << 4];
    float m = row[0];
#pragma unroll
    for (int j = 1; j < 16; ++j) m = fmaxf(m, row[j]);
    float ssum = 0.f;
#pragma unroll
    for (int j = 0; j < 16; ++j) ssum += expf(row[j] - m);
    attn[t] = expf(e - m) / ssum;
}

// ---------------------------------------------------------------------------
// combine: cmb[b, px in p][c] = sum_q attn[b,p,q] * x2p[b, q-px][c] (NHWC bf16)
// ---------------------------------------------------------------------------
__global__ __launch_bounds__(256) void combine_kernel(
    const float* __restrict__ attn, const ushort_t* __restrict__ x2p,
    ushort_t* __restrict__ cmb)
{
    int gid = blockIdx.x * 256 + threadIdx.x;   // B*65536*8
    int cq = gid & 7;
    int pxg = (gid >> 3) & 65535;
    int b = gid >> 19;
    int y = pxg >> 8, x = pxg & 255;
    int p = (y >> 6) * 4 + (x >> 6);
    int i = y & 63, j = x & 63;
    const float* arow = attn + (size_t)(b * 16 + p) * 16;
    float s[8];
#pragma unroll
    for (int k = 0; k < 8; ++k) s[k] = 0.f;
#pragma unroll
    for (int q = 0; q < 16; ++q) {
        float a = arow[q];
        const ushort_t* sp = x2p +
            ((size_t)(b * 256 + (q >> 2) * 64 + i) * 256 + (q & 3) * 64 + j) * 64 + cq * 8;
        uint4 v = *(const uint4*)sp;
        unsigned uu[4] = {v.x, v.y, v.z, v.w};
#pragma unroll
        for (int h = 0; h < 4; ++h) {
            s[h * 2]     = fmaf(a, bf2f((ushort_t)(uu[h] & 0xffffu)), s[h * 2]);
            s[h * 2 + 1] = fmaf(a, bf2f((ushort_t)(uu[h] >> 16)),     s[h * 2 + 1]);
        }
    }
    uint4 o;
    o.x = (unsigned)f2bf(s[0]) | ((unsigned)f2bf(s[1]) << 16);
    o.y = (unsigned)f2bf(s[2]) | ((unsigned)f2bf(s[3]) << 16);
    o.z = (unsigned)f2bf(s[4]) | ((unsigned)f2bf(s[5]) << 16);
    o.w = (unsigned)f2bf(s[6]) | ((unsigned)f2bf(s[7]) << 16);
    *(uint4*)(cmb + ((size_t)b * 65536 + pxg) * 64 + cq * 8) = o;
}

// ---------------------------------------------------------------------------
extern "C" void kernel_launch(void* const* d_in, const int* in_sizes, int n_in,
                              void* d_out, int out_size, void* d_ws, size_t ws_size,
                              hipStream_t stream)
{
    const float* x     = (const float*)d_in[0];
    const float* pre_w = (const float*)d_in[1];
    const float* pre_b = (const float*)d_in[2];
    const float* c1_w  = (const float*)d_in[3];
    const float* c1_b  = (const float*)d_in[4];
    const float* c2_w  = (const float*)d_in[5];
    const float* c2_b  = (const float*)d_in[6];
    const float* p1_w  = (const float*)d_in[7];
    const float* p1_b  = (const float*)d_in[8];
    const float* p2_w  = (const float*)d_in[9];
    const float* p2_b  = (const float*)d_in[10];
    const float* fin_w = (const float*)d_in[11];
    const float* fin_b = (const float*)d_in[12];

    float* out = (float*)d_out;
    ushort_t* wsu = (ushort_t*)d_ws;

    const size_t U = UPL;              // 16,777,216 bf16 elems per 64-ch plane

    // ws layout (ushort units):
    ushort_t* xh   = wsu;              // [0,2U): x NHWC bf16; dead after pre
    ushort_t* x0b  = wsu + 2 * U;      // [2U,3U)
    ushort_t* tA   = wsu;              // [0,2U): branch L1 out (br stride U)
    ushort_t* tB   = wsu + 3 * U;      // [3U,5U): branch L2 out (br stride U)
    ushort_t* x12b = (ushort_t*)d_out; // [0,2U) of d_out: branch L3 out
    ushort_t* x1p  = tB;               // [3U,5U): p1x1 out (side stride U)
    ushort_t* x2p  = tB + U;
    ushort_t* cmb  = wsu;              // [0,U): after L2 consumed tA

    ushort_t* wpPre = wsu + 5 * U;                 // 73728
    ushort_t* wpC   = wpPre + 73728;               // 6*36864
    ushort_t* wpFin = wpC + 6 * 36864;             // 147456
    ushort_t* pw1b  = wpFin + 147456;              // 65536
    ushort_t* pw2b  = pw1b + 65536;                // 65536
    float* n1    = (float*)(pw2b + 65536);
    float* n2    = n1 + 64;
    float* dotv  = n2 + 64;
    float* attn  = dotv + 1024;
    float* cbias = attn + 1024;                    // [2][3][64]

    const dim3 blk(256);

    // ---- fused prep (weights + zero accumulators + packed biases)
    prep_all_kernel<<<(574976 + 255) / 256, blk, 0, stream>>>(
        pre_w, c1_w, c2_w, fin_w, p1_w, p2_w, c1_b, c2_b,
        wpPre, wpC, wpFin, pw1b, pw2b, n1, cbias);

    // ---- x -> NHWC bf16
    x_to_nhwc_kernel<<<4096, blk, 0, stream>>>(x, xh);

    const dim3 gWide(256, 1, BB);      // wide tiles (4x * 64y), 64 co
    const dim3 gPair(256, 2, BB);      // wide tiles, y = branch
    const dim3 gFin(512, 1, BB);       // wide tiles * 2 co-halves (COPAIR)

    // ---- pre conv (128 -> 64)
    wconv3x3<128, 128, 0, false, false><<<gWide, blk, 0, stream>>>(
        xh, xh, wpPre, pre_b, nullptr, x0b, 64, 0, 0, 0, 0);

    // ---- branch pair, 3 layers (both branches per dispatch, wide kernel)
    wconv3x3<64, 64, 0, true, false><<<gPair, blk, 0, stream>>>(
        x0b, x0b, wpC, cbias, nullptr, tA, 64,
        0, 3 * 36864, 192, U);
    wconv3x3<64, 64, 0, true, false><<<gPair, blk, 0, stream>>>(
        tA, tA, wpC + 36864, cbias + 64, nullptr, tB, 64,
        U, 3 * 36864, 192, U);
    wconv3x3<64, 64, 1, true, false><<<gPair, blk, 0, stream>>>(
        tB, tB, wpC + 2 * 36864, cbias + 128, x0b, x12b, 64,
        U, 3 * 36864, 192, U);

    // ---- per-patch 1x1 (MFMA, both sides) + fused norms
    const dim3 pgrid(16, BB * PP, 2);
    patch1x1_mfma<<<pgrid, blk, 0, stream>>>(x12b, pw1b, p1_b, p2_b, x1p, n1);

    // ---- pairwise dots (MFMA, split-K atomics)
    const dim3 dgrid(64, BB);
    patch_dots_mfma<<<dgrid, blk, 0, stream>>>(x1p, x2p, dotv);

    // ---- attention
    attn_kernel<<<1, 1024, 0, stream>>>(n1, n2, dotv, attn);

    // ---- combine
    combine_kernel<<<BB * 65536 * 8 / 256, blk, 0, stream>>>(attn, x2p, cmb);

    // ---- final conv: concat[cmb, x0b] -> d_out fp32 NCHW (+x residual),
    //      co-paired on swizzled ids (same XCD)
    wconv3x3<128, 64, 2, false, true><<<gFin, blk, 0, stream>>>(
        cmb, x0b, wpFin, fin_b, x, out, 128, 0, 0, 0, 0);
}

// Round 13
// 534.393 us; speedup vs baseline: 1.1352x; 1.1352x over previous
//
#include <hip/hip_runtime.h>
#include <hip/hip_bf16.h>

#define BB   4
#define HH   256
#define WW   256
#define INCH 128
#define MIDC 64
#define NPAT 4
#define PP   16
#define PS   64

typedef __bf16 bf16x8 __attribute__((ext_vector_type(8)));
typedef float f32x4 __attribute__((ext_vector_type(4)));
typedef unsigned short ushort_t;

#define UPL 16777216UL   // one 64-ch bf16 plane set: B*H*W*64 elements

__device__ inline ushort_t f2bf(float f) {
    unsigned u = __float_as_uint(f);
    unsigned r = (u + 0x7FFFu + ((u >> 16) & 1u)) >> 16;
    return (ushort_t)r;
}
__device__ inline float bf2f(ushort_t h) {
    return __uint_as_float(((unsigned)h) << 16);
}
__device__ inline f32x4 mfma16(uint4 a, uint4 b, f32x4 c) {
    return __builtin_amdgcn_mfma_f32_16x16x32_bf16(
        __builtin_bit_cast(bf16x8, a), __builtin_bit_cast(bf16x8, b), c, 0, 0, 0);
}

// ---------------------------------------------------------------------------
// fused setup: blockIdx.x < 4096 -> x fp32 NCHW -> bf16 NHWC (LDS transpose);
// else -> weight prep (conv wts -> [9][COUT][CIN] bf16; p1/p2 -> bf16;
// zero n1/n2/dotv; pack c1_b/c2_b into cbias[2][3][64]).
// ---------------------------------------------------------------------------
__global__ __launch_bounds__(256) void setup_kernel(
    const float* __restrict__ x,     ushort_t* __restrict__ xh,
    const float* __restrict__ pre_w, const float* __restrict__ c1_w,
    const float* __restrict__ c2_w,  const float* __restrict__ fin_w,
    const float* __restrict__ p1_w,  const float* __restrict__ p2_w,
    const float* __restrict__ c1_b,  const float* __restrict__ c2_b,
    ushort_t* __restrict__ wpPre, ushort_t* __restrict__ wpC,
    ushort_t* __restrict__ wpFin, ushort_t* __restrict__ pw1b,
    ushort_t* __restrict__ pw2b,  float* __restrict__ zbuf,
    float* __restrict__ cbias)
{
    __shared__ ushort_t sm[64 * 136];
    const int t = threadIdx.x;
    const int bx = blockIdx.x;
    if (bx < 4096) {                       // ---- x -> NHWC bf16
        const int b = bx >> 10;
        const int pxbase = (bx & 1023) * 64;
#pragma unroll
        for (int i = 0; i < 32; ++i) {
            int idx = i * 256 + t;         // [128 c][64 px]
            int c = idx >> 6, pxl = idx & 63;
            sm[pxl * 136 + c] = f2bf(x[((size_t)(b * 128 + c)) * 65536 + pxbase + pxl]);
        }
        __syncthreads();
#pragma unroll
        for (int i = 0; i < 4; ++i) {
            int idx = i * 256 + t;         // [64 px][16 quads]
            int pxl = idx >> 4, q = idx & 15;
            uint4 v = *(const uint4*)&sm[pxl * 136 + q * 8];
            *(uint4*)(xh + ((size_t)b * 65536 + pxbase + pxl) * 128 + q * 8) = v;
        }
        return;
    }
    int idx = (bx - 4096) * 256 + t;
    if (idx < 73728) {                       // pre: COUT=64, CIN=128
        int tap = idx % 9, ci = (idx / 9) % 128, co = idx / 1152;
        wpPre[(tap * 64 + co) * 128 + ci] = f2bf(pre_w[idx]);
    } else if (idx < 294912) {               // c1[0..2], c2[0..2]: 64x64
        int j = idx - 73728;
        int which = j / 36864, k = j % 36864;
        const float* src = (which < 3) ? (c1_w + (size_t)which * 36864)
                                       : (c2_w + (size_t)(which - 3) * 36864);
        int tap = k % 9, ci = (k / 9) % 64, co = k / 576;
        wpC[(size_t)which * 36864 + (tap * 64 + co) * 64 + ci] = f2bf(src[k]);
    } else if (idx < 442368) {               // fin: 128x128
        int k = idx - 294912;
        int tap = k % 9, ci = (k / 9) % 128, co = k / 1152;
        wpFin[(tap * 128 + co) * 128 + ci] = f2bf(fin_w[k]);
    } else if (idx < 507904) {
        pw1b[idx - 442368] = f2bf(p1_w[idx - 442368]);
    } else if (idx < 573440) {
        pw2b[idx - 507904] = f2bf(p2_w[idx - 507904]);
    } else if (idx < 574592) {
        zbuf[idx - 573440] = 0.f;            // n1(64)+n2(64)+dotv(1024)
    } else if (idx < 574784) {
        cbias[idx - 574592] = c1_b[idx - 574592];
    } else if (idx < 574976) {
        cbias[192 + idx - 574784] = c2_b[idx - 574784];
    }
}

// ---------------------------------------------------------------------------
// staging (v4 tile): 32-ci slab with halo (10 rows x 34 px) into regs
// ---------------------------------------------------------------------------
template<int CIN, int CSPLIT>
__device__ inline void stage10x34(const ushort_t* inA, const ushort_t* inB,
                                  int b, int y0, int x0, int t, int cb,
                                  uint4 (&stg)[6])
{
#pragma unroll
    for (int i = 0; i < 6; ++i) {
        int e = i * 256 + t;
        int pxl = e >> 2, quad = e & 3;
        int row = pxl / 34, xl = pxl - row * 34;
        int gy = y0 + row - 1, gx = x0 + xl - 1;
        bool ok = (e < 1360) && ((unsigned)gy < 256u) && ((unsigned)gx < 256u);
        int c0 = cb + quad * 8;
        const ushort_t* src; int nch, ch;
        if ((CSPLIT == CIN) || (c0 < CSPLIT)) { src = inA; nch = CSPLIT; ch = c0; }
        else { src = inB; nch = CIN - CSPLIT; ch = c0 - CSPLIT; }
        uint4 v = make_uint4(0u, 0u, 0u, 0u);
        if (ok) v = *(const uint4*)(src + ((size_t)((b * 256 + gy) * 256 + gx)) * nch + ch);
        stg[i] = v;
    }
}

// ---------------------------------------------------------------------------
// staging (wide tile): 32-ci slab with halo (6 rows x 68 px) into regs
// ---------------------------------------------------------------------------
template<int CIN, int CSPLIT>
__device__ inline void stage6x68(const ushort_t* inA, const ushort_t* inB,
                                 int b, int y0, int x0, int t, int cb,
                                 uint4 (&stg)[7])
{
#pragma unroll
    for (int i = 0; i < 7; ++i) {
        int e = i * 256 + t;
        int pxl = e >> 2, quad = e & 3;
        int row = pxl / 68, xl = pxl - row * 68;
        int gy = y0 + row - 1, gx = x0 + xl - 1;
        bool ok = (e < 1632) && ((unsigned)gy < 256u) && ((unsigned)gx < 256u);
        int c0 = cb + quad * 8;
        const ushort_t* src; int nch, ch;
        if ((CSPLIT == CIN) || (c0 < CSPLIT)) { src = inA; nch = CSPLIT; ch = c0; }
        else { src = inB; nch = CIN - CSPLIT; ch = c0 - CSPLIT; }
        uint4 v = make_uint4(0u, 0u, 0u, 0u);
        if (ok) v = *(const uint4*)(src + ((size_t)((b * 256 + gy) * 256 + gx)) * nch + ch);
        stg[i] = v;
    }
}

// ---------------------------------------------------------------------------
// v4 conv (measured best for CIN=64 branch layers, R11=540us):
// block 8 rows x 32 px x 64 co; wave = co-half x x-half x 8 rows;
// s-outer, af[2][9] preload; pad-36 LDS (conflict-free).
// PAIR: blockIdx.y = branch. OMODE: 0 bf16; 1 +bf16 residual.
// ---------------------------------------------------------------------------
template<int CIN, int CSPLIT, int OMODE, bool PAIR>
__global__ __launch_bounds__(256) void mconv3x3(
    const ushort_t* __restrict__ inA, const ushort_t* __restrict__ inB,
    const ushort_t* __restrict__ wgtT,
    const float* __restrict__ bias,
    const void* __restrict__ res,
    void* __restrict__ out,
    int COUT, size_t inStride, size_t wStride, size_t bStride, size_t outStride)
{
    constexpr int NCH = CIN / 32;
    __shared__ ushort_t sm[10 * 34 * 36];  // 24.5 KB

    const int t = threadIdx.x;
    const int nx = gridDim.x;
    const int bid = blockIdx.x;
    const int fid = (bid & 7) * (nx >> 3) + (bid >> 3);   // chunked XCD swizzle
    const int tile = fid;
    const int cog = PAIR ? 0 : blockIdx.y * 64;
    const int y0 = (tile >> 3) * 8;
    const int x0 = (tile & 7) * 32;
    const int br = PAIR ? blockIdx.y : 0;
    const ushort_t* inAb = inA + (size_t)br * inStride;
    const ushort_t* inBb = inB + (size_t)br * inStride;
    const ushort_t* wgt  = wgtT + (size_t)br * wStride;
    const float*    bs   = bias + (size_t)br * bStride;
    const int b = blockIdx.z;
    const int l = t & 63, w = t >> 6;
    const int lan15 = l & 15;
    const int g4 = l >> 4;
    const int k8 = g4 * 8;
    const int co0 = cog + (w & 1) * 32;
    const int xw = (w >> 1) * 16;

    f32x4 acc[2][8];
#pragma unroll
    for (int mt = 0; mt < 2; ++mt)
#pragma unroll
        for (int r = 0; r < 8; ++r) acc[mt][r] = (f32x4)0.f;

    uint4 stg[6];
    stage10x34<CIN, CSPLIT>(inAb, inBb, b, y0, x0, t, 0, stg);

    for (int cc = 0; cc < NCH; ++cc) {
        __syncthreads();
#pragma unroll
        for (int i = 0; i < 6; ++i) {
            int e = i * 256 + t;
            if (e < 1360) {
                int pxl = e >> 2, quad = e & 3;
                *(uint4*)&sm[pxl * 36 + quad * 8] = stg[i];
            }
        }
        __syncthreads();
        if (cc + 1 < NCH)
            stage10x34<CIN, CSPLIT>(inAb, inBb, b, y0, x0, t, (cc + 1) * 32, stg);

        const int cb = cc * 32;
        uint4 af[2][9];
#pragma unroll
        for (int mt = 0; mt < 2; ++mt)
#pragma unroll
            for (int tap = 0; tap < 9; ++tap)
                af[mt][tap] = *(const uint4*)(wgt +
                    ((size_t)tap * COUT + co0 + mt * 16 + lan15) * CIN + cb + k8);

#pragma unroll
        for (int s = 0; s < 10; ++s) {
#pragma unroll
            for (int dx = 0; dx < 3; ++dx) {
                const int pxl = s * 34 + xw + lan15 + dx;
                uint4 bv = *(const uint4*)&sm[pxl * 36 + k8];
#pragma unroll
                for (int dy = 0; dy < 3; ++dy) {
                    const int r = s - dy;
                    if (r >= 0 && r < 8) {
                        acc[0][r] = mfma16(af[0][dy * 3 + dx], bv, acc[0][r]);
                        acc[1][r] = mfma16(af[1][dy * 3 + dx], bv, acc[1][r]);
                    }
                }
            }
        }
    }

#pragma unroll
    for (int mt = 0; mt < 2; ++mt) {
#pragma unroll
        for (int r = 0; r < 8; ++r) {
            const int y = y0 + r;
            const int x = x0 + xw + lan15;
            const int codr = co0 + mt * 16 + g4 * 4;
            float v[4];
#pragma unroll
            for (int j = 0; j < 4; ++j)
                v[j] = fmaxf(acc[mt][r][j] + bs[codr + j], 0.f);
            const size_t pix = (size_t)(b * 256 + y) * 256 + x;
            if constexpr (OMODE == 1) {
                const ushort_t* rp = (const ushort_t*)res + pix * 64 + codr;
#pragma unroll
                for (int j = 0; j < 4; ++j) v[j] += bf2f(rp[j]);
            }
            uint2 pk;
            pk.x = (unsigned)f2bf(v[0]) | ((unsigned)f2bf(v[1]) << 16);
            pk.y = (unsigned)f2bf(v[2]) | ((unsigned)f2bf(v[3]) << 16);
            *(uint2*)((ushort_t*)out + (size_t)br * outStride + pix * COUT + codr) = pk;
        }
    }
}

// ---------------------------------------------------------------------------
// wide conv (measured best for CIN=128 pre/final, R11=540us):
// block tile 4 rows x 64 px x 64 co; wave = co-half x row-pair, 4 x-cols.
// LDS [6 rows][68 px][32 ci] linear (~6e6 conflict cy, accepted: cheaper
// than swizzle VGPRs). XCD-chunked swizzle; COPAIR: co-halves same XCD.
// OMODE: 0 = bf16 NHWC out; 2 = fp32 NCHW out + fp32 NCHW residual.
// ---------------------------------------------------------------------------
template<int CIN, int CSPLIT, int OMODE, bool COPAIR>
__global__ __launch_bounds__(256) void wconv3x3(
    const ushort_t* __restrict__ inA, const ushort_t* __restrict__ inB,
    const ushort_t* __restrict__ wgtT,   // [9][COUT][CIN] bf16
    const float* __restrict__ bias,
    const void* __restrict__ res,
    void* __restrict__ out,
    int COUT)
{
    constexpr int NCH = CIN / 32;
    __shared__ ushort_t sm[6 * 68 * 32];   // 26112 B

    const int t = threadIdx.x;
    const int nx = gridDim.x;              // % 8 == 0
    const int bid = blockIdx.x;
    const int fid = (bid & 7) * (nx >> 3) + (bid >> 3);
    int tile, cog;
    if (COPAIR) { tile = fid >> 1; cog = (fid & 1) * 64; }
    else        { tile = fid;      cog = blockIdx.y * 64; }
    const int y0 = (tile >> 2) * 4;        // 64 y-tiles
    const int x0 = (tile & 3) * 64;        // 4 x-tiles
    const int b = blockIdx.z;
    const int l = t & 63, w = t >> 6;
    const int lan15 = l & 15;
    const int g4 = l >> 4;
    const int k8 = g4 * 8;
    const int co0 = cog + (w & 1) * 32;
    const int wrow0 = (w >> 1) * 2;

    f32x4 acc[2][8];
#pragma unroll
    for (int mt = 0; mt < 2; ++mt)
#pragma unroll
        for (int nt = 0; nt < 8; ++nt) acc[mt][nt] = (f32x4)0.f;

    uint4 stg[7];
    stage6x68<CIN, CSPLIT>(inA, inB, b, y0, x0, t, 0, stg);

    for (int cc = 0; cc < NCH; ++cc) {
        __syncthreads();
#pragma unroll
        for (int i = 0; i < 7; ++i) {
            int e = i * 256 + t;
            if (e < 1632) {
                int pxl = e >> 2, quad = e & 3;
                *(uint4*)&sm[pxl * 32 + quad * 8] = stg[i];
            }
        }
        __syncthreads();
        if (cc + 1 < NCH)
            stage6x68<CIN, CSPLIT>(inA, inB, b, y0, x0, t, (cc + 1) * 32, stg);

        const int cb = cc * 32;
        uint4 af[2][9];
#pragma unroll
        for (int mt = 0; mt < 2; ++mt)
#pragma unroll
            for (int tap = 0; tap < 9; ++tap)
                af[mt][tap] = *(const uint4*)(wgtT +
                    ((size_t)tap * COUT + co0 + mt * 16 + lan15) * CIN + cb + k8);

#pragma unroll
        for (int rr = 0; rr < 4; ++rr) {
            const int r = wrow0 + rr;
#pragma unroll
            for (int col = 0; col < 4; ++col) {
#pragma unroll
                for (int dx = 0; dx < 3; ++dx) {
                    const int xc = col * 16 + lan15 + dx;
                    uint4 bv = *(const uint4*)&sm[(r * 68 + xc) * 32 + k8];
#pragma unroll
                    for (int drow = 0; drow < 2; ++drow) {
                        const int dy = rr - drow;
                        if (dy >= 0 && dy < 3) {
                            const int tap = dy * 3 + dx;
                            const int nt = drow * 4 + col;
                            acc[0][nt] = mfma16(af[0][tap], bv, acc[0][nt]);
                            acc[1][nt] = mfma16(af[1][tap], bv, acc[1][nt]);
                        }
                    }
                }
            }
        }
    }

    // epilogue
#pragma unroll
    for (int mt = 0; mt < 2; ++mt) {
#pragma unroll
        for (int nt = 0; nt < 8; ++nt) {
            const int y = y0 + wrow0 + (nt >> 2);
            const int x = x0 + (nt & 3) * 16 + lan15;
            const int codr = co0 + mt * 16 + g4 * 4;
            float v[4];
#pragma unroll
            for (int j = 0; j < 4; ++j)
                v[j] = fmaxf(acc[mt][nt][j] + bias[codr + j], 0.f);
            if constexpr (OMODE == 2) {
                const float* rf = (const float*)res;
                float* of = (float*)out;
#pragma unroll
                for (int j = 0; j < 4; ++j) {
                    size_t oi = ((size_t)(b * COUT + codr + j) * 256 + y) * 256 + x;
                    of[oi] = v[j] + rf[oi];
                }
            } else {
                const size_t pix = (size_t)(b * 256 + y) * 256 + x;
                uint2 pk;
                pk.x = (unsigned)f2bf(v[0]) | ((unsigned)f2bf(v[1]) << 16);
                pk.y = (unsigned)f2bf(v[2]) | ((unsigned)f2bf(v[3]) << 16);
                *(uint2*)((ushort_t*)out + pix * COUT + codr) = pk;
            }
        }
    }
}

// ---------------------------------------------------------------------------
// per-patch 1x1 conv via MFMA (bf16 NHWC -> bf16 NHWC) + fused norm atomics.
// blockIdx.z selects side (x1/x2).
// ---------------------------------------------------------------------------
__global__ __launch_bounds__(256) void patch1x1_mfma(
    const ushort_t* __restrict__ in0, const ushort_t* __restrict__ pwb0,
    const float* __restrict__ bias1, const float* __restrict__ bias2,
    ushort_t* __restrict__ outp0, float* __restrict__ nrm0)
{
    __shared__ ushort_t smp[256 * 72];
    const int side = blockIdx.z;
    const ushort_t* in  = in0  + (size_t)side * UPL;
    const ushort_t* pwb = pwb0 + side * 65536;
    const float*   bias = side ? bias2 : bias1;
    ushort_t*      outp = outp0 + (size_t)side * UPL;
    float*         nrm  = nrm0 + side * 64;

    const int t = threadIdx.x;
    const int bx = blockIdx.x;         // iy0 = bx*4
    const int bp = blockIdx.y;
    const int b = bp >> 4, p = bp & 15;
    const int py = (p >> 2) * 64, px0 = (p & 3) * 64;
    const int l = t & 63, w = t >> 6;
    const int lan15 = l & 15, k8 = (l >> 4) * 8;

#pragma unroll
    for (int i = 0; i < 8; ++i) {
        int idx = i * 256 + t;         // [256 px][8 quads]
        int px = idx >> 3, q = idx & 7;
        int y = py + bx * 4 + (px >> 6), x = px0 + (px & 63);
        uint4 v = *(const uint4*)(in + ((size_t)(b * 256 + y) * 256 + x) * 64 + q * 8);
        *(uint4*)&smp[px * 72 + q * 8] = v;
    }
    __syncthreads();

    uint4 af[4][2];
#pragma unroll
    for (int mt = 0; mt < 4; ++mt)
#pragma unroll
        for (int kk = 0; kk < 2; ++kk)
            af[mt][kk] = *(const uint4*)(pwb + (size_t)p * 4096 +
                                         (mt * 16 + lan15) * 64 + kk * 32 + k8);

    f32x4 acc[4][4];
#pragma unroll
    for (int mt = 0; mt < 4; ++mt)
#pragma unroll
        for (int j = 0; j < 4; ++j) acc[mt][j] = (f32x4)0.f;

#pragma unroll
    for (int kk = 0; kk < 2; ++kk)
#pragma unroll
        for (int j = 0; j < 4; ++j) {
            int px = (w * 4 + j) * 16 + lan15;
            uint4 bv = *(const uint4*)&smp[px * 72 + kk * 32 + k8];
#pragma unroll
            for (int mt = 0; mt < 4; ++mt)
                acc[mt][j] = mfma16(af[mt][kk], bv, acc[mt][j]);
        }

    float nsum = 0.f;
#pragma unroll
    for (int mt = 0; mt < 4; ++mt)
#pragma unroll
        for (int j = 0; j < 4; ++j) {
            int px = (w * 4 + j) * 16 + lan15;
            int y = py + bx * 4 + (px >> 6), x = px0 + (px & 63);
            int d0 = mt * 16 + (l >> 4) * 4;
            float v[4];
#pragma unroll
            for (int r = 0; r < 4; ++r) {
                v[r] = acc[mt][j][r] + bias[p * 64 + d0 + r];
                nsum = fmaf(v[r], v[r], nsum);
            }
            uint2 pk;
            pk.x = (unsigned)f2bf(v[0]) | ((unsigned)f2bf(v[1]) << 16);
            pk.y = (unsigned)f2bf(v[2]) | ((unsigned)f2bf(v[3]) << 16);
            *(uint2*)(outp + ((size_t)(b * 256 + y) * 256 + x) * 64 + d0) = pk;
        }

#pragma unroll
    for (int off = 32; off > 0; off >>= 1) nsum += __shfl_down(nsum, off);
    if (l == 0) atomicAdd(&nrm[b * 16 + p], nsum);
}

// ---------------------------------------------------------------------------
// pairwise patch dots via MFMA: dotv[b][p][q] += f1_p . f2_q
// ---------------------------------------------------------------------------
__global__ __launch_bounds__(256) void patch_dots_mfma(
    const ushort_t* __restrict__ f1, const ushort_t* __restrict__ f2,
    float* __restrict__ dotv)
{
    __shared__ float rbuf[4][64][4];
    const int t = threadIdx.x;
    const int kb = blockIdx.x;         // patch-local row iy
    const int b = blockIdx.y;
    const int l = t & 63, w = t >> 6;
    const int lan15 = l & 15, k8q = (l >> 4) * 8;
    const int p = lan15;
    const int py = (p >> 2) * 64, px0 = (p & 3) * 64;
    const size_t rowbase = ((size_t)(b * 256 + py + kb) * 256 + px0) * 64;

    f32x4 acc = (f32x4)0.f;
    for (int ixl = 0; ixl < 16; ++ixl) {
        const size_t pa = rowbase + (size_t)(w * 16 + ixl) * 64 + k8q;
#pragma unroll
        for (int c0 = 0; c0 < 64; c0 += 32) {
            uint4 av = *(const uint4*)(f1 + pa + c0);
            uint4 bv = *(const uint4*)(f2 + pa + c0);
            acc = mfma16(av, bv, acc);
        }
    }
#pragma unroll
    for (int r = 0; r < 4; ++r) rbuf[w][l][r] = acc[r];
    __syncthreads();
    if (t < 64) {
#pragma unroll
        for (int r = 0; r < 4; ++r) {
            float s = rbuf[0][t][r] + rbuf[1][t][r] + rbuf[2][t][r] + rbuf[3][t][r];
            int pp = (t >> 4) * 4 + r, qq = t & 15;
            atomicAdd(&dotv[b * 256 + pp * 16 + qq], s);
        }
    }
}

// ---------------------------------------------------------------------------
// attention weights: d = n1+n2-2dot, diag=1e8, attn = softmax(exp(-d))
// ---------------------------------------------------------------------------
__global__ __launch_bounds__(1024) void attn_kernel(
    const float* __restrict__ n1, const float* __restrict__ n2,
    const float* __restrict__ dotv, float* __restrict__ attn)
{
    __shared__ float tv[1024];
    int t = threadIdx.x;
    int b = t >> 8, p = (t >> 4) & 15, q = t & 15;
    float d = n1[b * 16 + p] + n2[b * 16 + q] - 2.f * dotv[t];
    if (p == q) d = 1e8f;
    float e = expf(-d);
    tv[t] = e;
    __syncthreads();
    const float* row = &tv[(t >> 4) << 4];
    float m = row[0];
#pragma unroll
    for (int j = 1; j < 16; ++j) m = fmaxf(m, row[j]);
    float ssum = 0.f;
#pragma unroll
    for (int j = 0; j < 16; ++j) ssum += expf(row[j] - m);
    attn[t] = expf(e - m) / ssum;
}

// ---------------------------------------------------------------------------
// combine: cmb[b, px in p][c] = sum_q attn[b,p,q] * x2p[b, q-px][c] (NHWC bf16)
// ---------------------------------------------------------------------------
__global__ __launch_bounds__(256) void combine_kernel(
    const float* __restrict__ attn, const ushort_t* __restrict__ x2p,
    ushort_t* __restrict__ cmb)
{
    int gid = blockIdx.x * 256 + threadIdx.x;   // B*65536*8
    int cq = gid & 7;
    int pxg = (gid >> 3) & 65535;
    int b = gid >> 19;
    int y = pxg >> 8, x = pxg & 255;
    int p = (y >> 6) * 4 + (x >> 6);
    int i = y & 63, j = x & 63;
    const float* arow = attn + (size_t)(b * 16 + p) * 16;
    float s[8];
#pragma unroll
    for (int k = 0; k < 8; ++k) s[k] = 0.f;
#pragma unroll
    for (int q = 0; q < 16; ++q) {
        float a = arow[q];
        const ushort_t* sp = x2p +
            ((size_t)(b * 256 + (q >> 2) * 64 + i) * 256 + (q & 3) * 64 + j) * 64 + cq * 8;
        uint4 v = *(const uint4*)sp;
        unsigned uu[4] = {v.x, v.y, v.z, v.w};
#pragma unroll
        for (int h = 0; h < 4; ++h) {
            s[h * 2]     = fmaf(a, bf2f((ushort_t)(uu[h] & 0xffffu)), s[h * 2]);
            s[h * 2 + 1] = fmaf(a, bf2f((ushort_t)(uu[h] >> 16)),     s[h * 2 + 1]);
        }
    }
    uint4 o;
    o.x = (unsigned)f2bf(s[0]) | ((unsigned)f2bf(s[1]) << 16);
    o.y = (unsigned)f2bf(s[2]) | ((unsigned)f2bf(s[3]) << 16);
    o.z = (unsigned)f2bf(s[4]) | ((unsigned)f2bf(s[5]) << 16);
    o.w = (unsigned)f2bf(s[6]) | ((unsigned)f2bf(s[7]) << 16);
    *(uint4*)(cmb + ((size_t)b * 65536 + pxg) * 64 + cq * 8) = o;
}

// ---------------------------------------------------------------------------
extern "C" void kernel_launch(void* const* d_in, const int* in_sizes, int n_in,
                              void* d_out, int out_size, void* d_ws, size_t ws_size,
                              hipStream_t stream)
{
    const float* x     = (const float*)d_in[0];
    const float* pre_w = (const float*)d_in[1];
    const float* pre_b = (const float*)d_in[2];
    const float* c1_w  = (const float*)d_in[3];
    const float* c1_b  = (const float*)d_in[4];
    const float* c2_w  = (const float*)d_in[5];
    const float* c2_b  = (const float*)d_in[6];
    const float* p1_w  = (const float*)d_in[7];
    const float* p1_b  = (const float*)d_in[8];
    const float* p2_w  = (const float*)d_in[9];
    const float* p2_b  = (const float*)d_in[10];
    const float* fin_w = (const float*)d_in[11];
    const float* fin_b = (const float*)d_in[12];

    float* out = (float*)d_out;
    ushort_t* wsu = (ushort_t*)d_ws;

    const size_t U = UPL;              // 16,777,216 bf16 elems per 64-ch plane

    // ws layout (ushort units):
    ushort_t* xh   = wsu;              // [0,2U): x NHWC bf16; dead after pre
    ushort_t* x0b  = wsu + 2 * U;      // [2U,3U)
    ushort_t* tA   = wsu;              // [0,2U): branch L1 out (br stride U)
    ushort_t* tB   = wsu + 3 * U;      // [3U,5U): branch L2 out (br stride U)
    ushort_t* x12b = (ushort_t*)d_out; // [0,2U) of d_out: branch L3 out
    ushort_t* x1p  = tB;               // [3U,5U): p1x1 out (side stride U)
    ushort_t* x2p  = tB + U;
    ushort_t* cmb  = wsu;              // [0,U): after L2 consumed tA

    ushort_t* wpPre = wsu + 5 * U;                 // 73728
    ushort_t* wpC   = wpPre + 73728;               // 6*36864
    ushort_t* wpFin = wpC + 6 * 36864;             // 147456
    ushort_t* pw1b  = wpFin + 147456;              // 65536
    ushort_t* pw2b  = pw1b + 65536;                // 65536
    float* n1    = (float*)(pw2b + 65536);
    float* n2    = n1 + 64;
    float* dotv  = n2 + 64;
    float* attn  = dotv + 1024;
    float* cbias = attn + 1024;                    // [2][3][64]

    const dim3 blk(256);

    // ---- fused setup: x->NHWC (4096 blocks) + weight prep (2246 blocks)
    setup_kernel<<<4096 + (574976 + 255) / 256, blk, 0, stream>>>(
        x, xh, pre_w, c1_w, c2_w, fin_w, p1_w, p2_w, c1_b, c2_b,
        wpPre, wpC, wpFin, pw1b, pw2b, n1, cbias);

    const dim3 gWide(256, 1, BB);      // wide tiles (4x * 64y), 64 co
    const dim3 gPair(256, 2, BB);      // v4 tiles, y = branch
    const dim3 gFin(512, 1, BB);       // wide tiles * 2 co-halves (COPAIR)

    // ---- pre conv (128 -> 64): wide kernel
    wconv3x3<128, 128, 0, false><<<gWide, blk, 0, stream>>>(
        xh, xh, wpPre, pre_b, nullptr, x0b, 64);

    // ---- branch pair, 3 layers (both branches per dispatch, v4 kernel)
    mconv3x3<64, 64, 0, true><<<gPair, blk, 0, stream>>>(
        x0b, x0b, wpC, cbias, nullptr, tA, 64,
        0, 3 * 36864, 192, U);
    mconv3x3<64, 64, 0, true><<<gPair, blk, 0, stream>>>(
        tA, tA, wpC + 36864, cbias + 64, nullptr, tB, 64,
        U, 3 * 36864, 192, U);
    mconv3x3<64, 64, 1, true><<<gPair, blk, 0, stream>>>(
        tB, tB, wpC + 2 * 36864, cbias + 128, x0b, x12b, 64,
        U, 3 * 36864, 192, U);

    // ---- per-patch 1x1 (MFMA, both sides) + fused norms
    const dim3 pgrid(16, BB * PP, 2);
    patch1x1_mfma<<<pgrid, blk, 0, stream>>>(x12b, pw1b, p1_b, p2_b, x1p, n1);

    // ---- pairwise dots (MFMA, split-K atomics)
    const dim3 dgrid(64, BB);
    patch_dots_mfma<<<dgrid, blk, 0, stream>>>(x1p, x2p, dotv);

    // ---- attention
    attn_kernel<<<1, 1024, 0, stream>>>(n1, n2, dotv, attn);

    // ---- combine
    combine_kernel<<<BB * 65536 * 8 / 256, blk, 0, stream>>>(attn, x2p, cmb);

    // ---- final conv: concat[cmb, x0b] -> d_out fp32 NCHW (+x residual),
    //      wide kernel, co-paired on swizzled ids (same XCD)
    wconv3x3<128, 64, 2, true><<<gFin, blk, 0, stream>>>(
        cmb, x0b, wpFin, fin_b, x, out, 128);
}